// Round 7
// baseline (645.091 us; speedup 1.0000x reference)
//
#include <hip/hip_runtime.h>

typedef unsigned short u16;
typedef unsigned int u32;
typedef __attribute__((ext_vector_type(4))) float f32x4;
typedef __attribute__((ext_vector_type(4))) u16 u16x4;
typedef __attribute__((ext_vector_type(8))) u16 u16x8;
typedef __attribute__((ext_vector_type(8))) __bf16 bf16x8;

#define FLA_EPS 1e-6f

__device__ __forceinline__ u16 f2b(float f) {
  union { float f; u32 u; } v; v.f = f;
  u32 r = v.u + 0x7FFFu + ((v.u >> 16) & 1u);
  return (u16)(r >> 16);
}
__device__ __forceinline__ float b2f(u16 h) {
  union { u32 u; float f; } v; v.u = ((u32)h) << 16; return v.f;
}
__device__ __forceinline__ float bsum8(bf16x8 v) {
  union { bf16x8 b; u16x8 u; } x; x.b = v;
  float s = 0.f;
#pragma unroll
  for (int e = 0; e < 8; ++e) s += b2f(x.u[e]);
  return s;
}
__device__ __forceinline__ void g2l16(const void* g, void* l) {
  __builtin_amdgcn_global_load_lds((__attribute__((address_space(1))) void*)g,
                                   (__attribute__((address_space(3))) void*)l,
                                   16, 0, 0);
}

// ---------------- fused prep: cast x, fold proj, transpose Wv/Wo, zero kv accum ----
__global__ void __launch_bounds__(256) prep(const float* __restrict__ x,
                                            const float* __restrict__ Wq,
                                            const float* __restrict__ Wk,
                                            const float* __restrict__ Wv,
                                            const float* __restrict__ Wo,
                                            const float* __restrict__ proj,
                                            u16* __restrict__ xb,
                                            u16* __restrict__ WqkvT,
                                            u16* __restrict__ woT,
                                            float* __restrict__ zbase) {
  __shared__ __align__(16) char smem[33280];
  const int blk = blockIdx.x;
  const int t = threadIdx.x;
  if (blk < 16384) {
    size_t i = (size_t)blk * 256 + t;
    const f32x4* p = (const f32x4*)x + i * 2;
    f32x4 a = p[0], b = p[1];
    u16x8 r;
    r[0] = f2b(a[0]); r[1] = f2b(a[1]); r[2] = f2b(a[2]); r[3] = f2b(a[3]);
    r[4] = f2b(b[0]); r[5] = f2b(b[1]); r[6] = f2b(b[2]); r[7] = f2b(b[3]);
    ((u16x8*)xb)[i] = r;
  } else if (blk < 16896) {
    const int b2 = blk - 16384;
    const int kbase = (b2 & 15) * 64, h = (b2 >> 4) & 15, sel = b2 >> 8;
    float (*Wt)[65] = (float(*)[65])smem;
    float (*P)[64] = (float(*)[64])(smem + 16640);
    const float* W = sel ? Wk : Wq;
    {
      int row = t >> 2, cb = (t & 3) * 16;
#pragma unroll
      for (int i = 0; i < 4; ++i) {
        f32x4 vv = *(const f32x4*)(W + (size_t)(kbase + row) * 1024 + h * 64 + cb + i * 4);
        Wt[row][cb + i * 4 + 0] = vv[0]; Wt[row][cb + i * 4 + 1] = vv[1];
        Wt[row][cb + i * 4 + 2] = vv[2]; Wt[row][cb + i * 4 + 3] = vv[3];
        f32x4 pp = *(const f32x4*)(proj + (size_t)row * 64 + cb + i * 4);
        P[row][cb + i * 4 + 0] = pp[0]; P[row][cb + i * 4 + 1] = pp[1];
        P[row][cb + i * 4 + 2] = pp[2]; P[row][cb + i * 4 + 3] = pp[3];
      }
    }
    __syncthreads();
    const int kk = t & 63, fg = (t >> 6) * 16;
    float acc[16] = {};
    for (int d = 0; d < 64; ++d) {
      float w = Wt[kk][d];
#pragma unroll
      for (int ff = 0; ff < 16; ++ff) acc[ff] = fmaf(w, P[d][fg + ff], acc[ff]);
    }
#pragma unroll
    for (int ff = 0; ff < 16; ++ff)
      WqkvT[(size_t)(sel * 1024 + h * 64 + fg + ff) * 1024 + kbase + kk] = f2b(acc[ff]);
  } else if (blk < 17408) {
    const bool isV = blk < 17152;
    const int b3 = blk - (isV ? 16896 : 17152);
    const float* W = isV ? Wv : Wo;
    u16* Wt_out = isV ? (WqkvT + (size_t)2048 * 1024) : woT;
    float (*tile)[65] = (float(*)[65])smem;
    const int k0 = (b3 & 15) * 64, n0 = (b3 >> 4) * 64;
    const int r = t >> 4, c4 = (t & 15) * 4;
#pragma unroll
    for (int i = 0; i < 4; ++i) {
      f32x4 vv = *(const f32x4*)(W + (size_t)(k0 + r + i * 16) * 1024 + n0 + c4);
      tile[r + i * 16][c4 + 0] = vv[0];
      tile[r + i * 16][c4 + 1] = vv[1];
      tile[r + i * 16][c4 + 2] = vv[2];
      tile[r + i * 16][c4 + 3] = vv[3];
    }
    __syncthreads();
#pragma unroll
    for (int i = 0; i < 4; ++i) {
      int nrow = r + i * 16;
      u16x4 o;
#pragma unroll
      for (int j = 0; j < 4; ++j) o[j] = f2b(tile[c4 + j][nrow]);
      *(u16x4*)(Wt_out + (size_t)(n0 + nrow) * 1024 + k0 + c4) = o;
    }
  } else {
    const size_t i = (size_t)(blk - 17408) * 256 + t;
    if (i < 66560) {
      f32x4 z = {0.f, 0.f, 0.f, 0.f};
      ((f32x4*)zbase)[i] = z;
    }
  }
}

// ---------------- 256x256 BK=64 SINGLE-buffered bf16 MFMA GEMM, 2 blocks/CU ----------
// R6 lesson: at 1 block/CU (128KB dbuf) every vmcnt(0)/barrier stalls the whole CU;
// two structurally different schedules both plateaued ~205-240us. This version trades
// pipeline depth for occupancy: 64KB LDS (one A tile + one B tile) -> 2 blocks/CU;
// per-tile stalls are covered by the co-resident block (m103 mechanism: TLP > depth).
// Fragment layout, XOR swizzles, register budget (~120 VGPR + 128 acc) identical to
// the proven R3 K-loop. Per tile:
//   vm0+bar (tile resident chip-wide) -> reads [bl4, afM0 8, bh4] with counted
//   lgkm(4)/(0) -> C1,C2 -> RD_A(M1)+lgkm0 -> C3 -> bar (all reads done) ->
//   stage(t+1), 8 DMA loads -> C4 (DMA flies under C4 + next head waits).
template <int NB, bool QKV>
__global__ void __launch_bounds__(512) gemm256(const u16* __restrict__ Ax,
                                               const u16* __restrict__ Bt,
                                               u16* __restrict__ qo, u16* __restrict__ ko,
                                               u16* __restrict__ vo,
                                               float* __restrict__ Cf,
                                               const float* __restrict__ bias) {
  __shared__ __align__(16) u16 lds[32768];   // 64KB: As 32KB + Bs 32KB
  const int tid = threadIdx.x;
  const int flat = blockIdx.x;
  const int xcd = flat & 7, slot = flat >> 3;
  const int pos = slot & 7, g = slot >> 3;
  const int nc = g % NB, mc = g / NB;
  const int m0 = (xcd * 16 + mc * 8 + pos) * 256;
  const int n0 = nc * 256;
  const int w = tid >> 6, l = tid & 63, quad = l >> 4, lr = l & 15;
  const int wm = w >> 2, wn = w & 3;
  u16* const As = lds;
  u16* const Bs = lds + 16384;
  const int c0 = ((quad * 16) ^ ((lr & 7) << 4)) >> 1;
  const int c1 = ((64 + quad * 16) ^ ((lr & 7) << 4)) >> 1;
  const int rst = tid >> 3;
  const int ksw8 = ((tid & 7) ^ (rst & 7)) * 8;
  const int tid8 = tid * 8;

  f32x4 acc[8][4] = {};
  bf16x8 af[4][2];
  bf16x8 bl[2][2];
  bf16x8 bh[2][2];

#define STG(SRC, ROW0, KT, DST) do {                                         \
    const u16* s_ = (SRC) + (size_t)((ROW0) + rst) * 1024 + (KT) + ksw8;     \
    g2l16(s_, (DST) + tid8);                                                 \
    g2l16(s_ + 64 * 1024, (DST) + 4096 + tid8);                              \
  } while (0)

#define RD_A(BASE, MH) do {                                                  \
    const u16* ap_ = (BASE) + wm * 8192 + (MH) * 4096;                       \
    _Pragma("unroll")                                                        \
    for (int ii = 0; ii < 4; ++ii) {                                         \
      const int ro_ = (ii * 16 + lr) * 64;                                   \
      af[ii][0] = *(const bf16x8*)(ap_ + ro_ + c0);                          \
      af[ii][1] = *(const bf16x8*)(ap_ + ro_ + c1);                          \
    } } while (0)

#define RD_B(DST2, BASE, J0) do {                                            \
    const u16* bp_ = (BASE) + (wn >> 1) * 8192 + (wn & 1) * 4096;            \
    _Pragma("unroll")                                                        \
    for (int jj = 0; jj < 2; ++jj) {                                         \
      const int ro_ = (((J0) + jj) * 16 + lr) * 64;                          \
      DST2[jj][0] = *(const bf16x8*)(bp_ + ro_ + c0);                        \
      DST2[jj][1] = *(const bf16x8*)(bp_ + ro_ + c1);                        \
    } } while (0)

#define CL(MH, BF2, NH) do {                                                 \
    __builtin_amdgcn_s_setprio(1);                                           \
    _Pragma("unroll")                                                        \
    for (int ii = 0; ii < 4; ++ii)                                           \
      _Pragma("unroll")                                                      \
      for (int jj = 0; jj < 2; ++jj)                                         \
        _Pragma("unroll")                                                    \
        for (int ks = 0; ks < 2; ++ks)                                       \
          acc[(MH) * 4 + ii][(NH) * 2 + jj] =                                \
              __builtin_amdgcn_mfma_f32_16x16x32_bf16(                       \
                  af[ii][ks], BF2[jj][ks],                                   \
                  acc[(MH) * 4 + ii][(NH) * 2 + jj], 0, 0, 0);               \
    __builtin_amdgcn_s_setprio(0);                                           \
  } while (0)

#define SB0() __builtin_amdgcn_sched_barrier(0)
#define WAIT_LGKM(N) do { asm volatile("s_waitcnt lgkmcnt(" #N ")" ::: "memory"); SB0(); } while (0)
#define WAIT_VM0()   do { asm volatile("s_waitcnt vmcnt(0)" ::: "memory"); SB0(); } while (0)
#define BARRIER()    do { asm volatile("s_barrier" ::: "memory"); SB0(); } while (0)

  // prologue: stage tile 0 (8 DMA loads/wave)
  STG(Ax, m0, 0, As); STG(Ax, m0 + 128, 0, As + 8192);
  STG(Bt, n0, 0, Bs); STG(Bt, n0 + 128, 0, Bs + 8192);

  for (int t = 0; t < 16; ++t) {
    WAIT_VM0();          // my stage(t) loads landed
    BARRIER();           // everyone's landed -> tile t readable
    RD_B(bl, Bs, 0);     // issue order: bl(4), afM0(8), bh(4)
    RD_A(As, 0);
    RD_B(bh, Bs, 2);
    SB0();
    WAIT_LGKM(4);        // bl + afM0 done (bh in flight)
    CL(0, bl, 0);
    WAIT_LGKM(0);        // bh done
    CL(0, bh, 1);
    SB0();
    RD_A(As, 1);         // af buffer dead (C2 issued)
    WAIT_LGKM(0);
    CL(1, bl, 0);
    SB0();
    BARRIER();           // all waves' tile-t reads complete -> WAR-safe to restage
    if (t < 15) {
      STG(Ax, m0,       (t + 1) * 64, As);
      STG(Ax, m0 + 128, (t + 1) * 64, As + 8192);
      STG(Bt, n0,       (t + 1) * 64, Bs);
      STG(Bt, n0 + 128, (t + 1) * 64, Bs + 8192);
    }
    CL(1, bh, 1);        // DMA flight hides under C4 + next-tile head
    SB0();
  }
#undef STG
#undef RD_A
#undef RD_B
#undef CL
#undef WAIT_LGKM
#undef WAIT_VM0
#undef BARRIER

  const int rbase = m0 + wm * 128 + quad * 4;
  if (QKV) {
    const int sel = n0 >> 10;
    if (sel == 0) {
      const int cb = (n0 & 1023) + wn * 64 + lr;
#pragma unroll
      for (int mi = 0; mi < 8; ++mi)
#pragma unroll
        for (int nj = 0; nj < 4; ++nj)
#pragma unroll
          for (int rr = 0; rr < 4; ++rr) {
            int row = rbase + mi * 16 + rr;
            float v = fmaxf(acc[mi][nj][rr], 0.0f) + FLA_EPS;
            qo[(size_t)row * 1024 + cb + nj * 16] = f2b(v);
          }
    } else {
      // k/v: LDS-bounce transpose in TWO 64KB passes (cols 0-127, 128-255).
      // LDS_T[c][r], c in [0,128): u16 addr = c*256 + (((r>>3)^(c&7))<<3) + (r&7)
      const bool isK = (sel == 1);
      u16* dstT = isK ? ko : vo;
      const int bI = m0 >> 13, s0 = m0 & 8191;
      const size_t cb0 = ((size_t)bI << 10) + (n0 & 1023);
#pragma unroll
      for (int p = 0; p < 2; ++p) {
        __syncthreads();   // K-loop reads done (p=0) / pass-0 stores done (p=1)
        if ((wn >> 1) == p) {
#pragma unroll
          for (int mi = 0; mi < 8; ++mi)
#pragma unroll
            for (int nj = 0; nj < 4; ++nj) {
              const int r0 = wm * 128 + mi * 16 + quad * 4;
              const int c = (wn & 1) * 64 + nj * 16 + lr;
              u16x4 pk;
#pragma unroll
              for (int rr = 0; rr < 4; ++rr) {
                float v = acc[mi][nj][rr];
                if (isK) v = fmaxf(v, 0.0f) + FLA_EPS;
                pk[rr] = f2b(v);
              }
              *(u16x4*)&lds[c * 256 + (((r0 >> 3) ^ (c & 7)) << 3) + (r0 & 7)] = pk;
            }
        }
        __syncthreads();
#pragma unroll
        for (int i = 0; i < 8; ++i) {
          const int c = w * 16 + i * 2 + (l >> 5);
          const int u = (l & 31) ^ (c & 7);
          u16x8 vv = *(const u16x8*)&lds[c * 256 + u * 8];
          *(u16x8*)(dstT + (cb0 + p * 128 + c) * 8192 + s0 + (l & 31) * 8) = vv;
        }
      }
    }
  } else {
#pragma unroll
    for (int mi = 0; mi < 8; ++mi)
#pragma unroll
      for (int nj = 0; nj < 4; ++nj) {
        const int cb = n0 + wn * 64 + nj * 16 + lr;
#pragma unroll
        for (int rr = 0; rr < 4; ++rr) {
          int row = rbase + mi * 16 + rr;
          Cf[(size_t)row * 1024 + cb] = acc[mi][nj][rr] + bias[cb];
        }
      }
  }
}

// ---------------- kv via MFMA, atomic accumulation into kvT/ksum ----------------
__global__ void __launch_bounds__(256) kv_mfma(const u16* __restrict__ kT,
                                               const u16* __restrict__ vT,
                                               float* __restrict__ kvT,
                                               float* __restrict__ ksum) {
  __shared__ __align__(16) u16 Av[2][4096];
  __shared__ __align__(16) u16 Bk[2][4096];
  const int tid = threadIdx.x;
  const int bh = blockIdx.x, chunk = blockIdx.y;
  const size_t n0 = (size_t)chunk * 1024;
  const u16* vbp = vT + (size_t)bh * 64 * 8192;
  const u16* kbp = kT + (size_t)bh * 64 * 8192;
  const int w = tid >> 6, l = tid & 63, quad = l >> 4, lr = l & 15;
  const int wd = w >> 1, wf = w & 1;
  const int dstg = tid >> 3, kc = tid & 7;
  const int sc0 = (kc ^ (dstg & 7)) * 8;
  f32x4 acc[2][2] = {};
  float ksm[2] = {0.f, 0.f};

#define KVSTG(BUF, T) do {                                                    \
    const size_t off_ = n0 + (size_t)(T) * 64;                                \
    g2l16(vbp + (size_t)dstg * 8192 + off_ + sc0, &Av[BUF][tid8_]);           \
    g2l16(vbp + (size_t)(dstg + 32) * 8192 + off_ + sc0, &Av[BUF][2048 + tid8_]); \
    g2l16(kbp + (size_t)dstg * 8192 + off_ + sc0, &Bk[BUF][tid8_]);           \
    g2l16(kbp + (size_t)(dstg + 32) * 8192 + off_ + sc0, &Bk[BUF][2048 + tid8_]); \
  } while (0)
  const int tid8_ = tid * 8;

  KVSTG(0, 0);
  for (int t = 0; t < 16; ++t) {
    const int buf = t & 1;
    if (t < 15) {
      KVSTG(buf ^ 1, t + 1);
      asm volatile("s_waitcnt vmcnt(4)" ::: "memory");
    } else {
      asm volatile("s_waitcnt vmcnt(0)" ::: "memory");
    }
    __builtin_amdgcn_sched_barrier(0);
    __builtin_amdgcn_s_barrier();
    bf16x8 av[2][2], bk[2][2];
#pragma unroll
    for (int di = 0; di < 2; ++di)
#pragma unroll
      for (int ks = 0; ks < 2; ++ks) {
        const int d = wd * 32 + di * 16 + lr;
        av[di][ks] = *(const bf16x8*)&Av[buf][d * 64 + ((ks * 4 + quad) ^ (d & 7)) * 8];
        const int f = wf * 32 + di * 16 + lr;
        bk[di][ks] = *(const bf16x8*)&Bk[buf][f * 64 + ((ks * 4 + quad) ^ (f & 7)) * 8];
      }
    asm volatile("s_waitcnt lgkmcnt(0)" ::: "memory");
    __builtin_amdgcn_sched_barrier(0);
#pragma unroll
    for (int di = 0; di < 2; ++di)
#pragma unroll
      for (int fj = 0; fj < 2; ++fj)
#pragma unroll
        for (int ks = 0; ks < 2; ++ks)
          acc[di][fj] = __builtin_amdgcn_mfma_f32_16x16x32_bf16(
              av[di][ks], bk[fj][ks], acc[di][fj], 0, 0, 0);
    if (w < 2) {
#pragma unroll
      for (int fj = 0; fj < 2; ++fj) {
        ksm[fj] += bsum8(bk[fj][0]);
        ksm[fj] += bsum8(bk[fj][1]);
      }
    }
    __builtin_amdgcn_s_barrier();
  }
#undef KVSTG

  float* pb = kvT + (size_t)bh * 4096;
#pragma unroll
  for (int di = 0; di < 2; ++di)
#pragma unroll
    for (int fj = 0; fj < 2; ++fj)
#pragma unroll
      for (int rr = 0; rr < 4; ++rr) {
        const int d = wd * 32 + di * 16 + quad * 4 + rr;
        const int f = wf * 32 + fj * 16 + lr;
        atomicAdd(&pb[d * 64 + f], acc[di][fj][rr]);
      }
  if (w < 2) {
#pragma unroll
    for (int fj = 0; fj < 2; ++fj) {
      float s = ksm[fj];
      s += __shfl_xor(s, 16, 64);
      s += __shfl_xor(s, 32, 64);
      if (l < 16)
        atomicAdd(&ksum[(size_t)bh * 64 + wf * 32 + fj * 16 + l], s);
    }
  }
}

// ---------------- num/den + normalize ----------------
__global__ void __launch_bounds__(256) num_den(const u16* __restrict__ qf,
                                               const float* __restrict__ kvT,
                                               const float* __restrict__ ksum,
                                               u16* __restrict__ outI) {
  __shared__ __align__(16) u16 As[128 * 64];
  __shared__ __align__(16) u16 Bs[64 * 64];
  __shared__ float ksum_s[64];
  __shared__ float den_s[128];
  const int t = threadIdx.x;
  const size_t tok0 = (size_t)blockIdx.x * 128;
  const int h = blockIdx.y;
  const int bh = (blockIdx.x >> 6) * 16 + h;
  const int w = t >> 6, l = t & 63, quad = l >> 4, lr = l & 15;
  const int trow = t >> 3, tcol = (t & 7) * 8;
#pragma unroll
  for (int i = 0; i < 4; ++i) {
    int r = i * 32 + trow;
    g2l16(qf + (tok0 + r) * 1024 + h * 64 + tcol, &As[r * 64 + tcol]);
  }
  {
    const float* kvb = kvT + (size_t)bh * 4096;
    int d = t >> 2, cb = (t & 3) * 16;
    u16x8 o0, o1;
#pragma unroll
    for (int q4 = 0; q4 < 2; ++q4) {
      f32x4 vv = *(const f32x4*)(kvb + d * 64 + cb + q4 * 4);
      o0[q4 * 4 + 0] = f2b(vv[0]); o0[q4 * 4 + 1] = f2b(vv[1]);
      o0[q4 * 4 + 2] = f2b(vv[2]); o0[q4 * 4 + 3] = f2b(vv[3]);
    }
#pragma unroll
    for (int q4 = 0; q4 < 2; ++q4) {
      f32x4 vv = *(const f32x4*)(kvb + d * 64 + cb + 8 + q4 * 4);
      o1[q4 * 4 + 0] = f2b(vv[0]); o1[q4 * 4 + 1] = f2b(vv[1]);
      o1[q4 * 4 + 2] = f2b(vv[2]); o1[q4 * 4 + 3] = f2b(vv[3]);
    }
    *(u16x8*)&Bs[d * 64 + cb] = o0;
    *(u16x8*)&Bs[d * 64 + cb + 8] = o1;
  }
  if (t < 64) ksum_s[t] = ksum[(size_t)bh * 64 + t];
  __syncthreads();
  if (t < 128) {
    float d = FLA_EPS;
#pragma unroll
    for (int jj = 0; jj < 64; ++jj) {
      int f = (t + jj) & 63;
      d += b2f(As[t * 64 + f]) * ksum_s[f];
    }
    den_s[t] = d;
  }
  __syncthreads();
  f32x4 acc[2][4] = {};
  const int wrow = w * 32;
#pragma unroll
  for (int ks = 0; ks < 2; ++ks) {
    bf16x8 af[2], bfr[4];
#pragma unroll
    for (int i = 0; i < 2; ++i)
      af[i] = *(const bf16x8*)&As[(wrow + i * 16 + lr) * 64 + ks * 32 + quad * 8];
#pragma unroll
    for (int j = 0; j < 4; ++j)
      bfr[j] = *(const bf16x8*)&Bs[(j * 16 + lr) * 64 + ks * 32 + quad * 8];
#pragma unroll
    for (int i = 0; i < 2; ++i)
#pragma unroll
      for (int j = 0; j < 4; ++j)
        acc[i][j] = __builtin_amdgcn_mfma_f32_16x16x32_bf16(af[i], bfr[j], acc[i][j], 0, 0, 0);
  }
#pragma unroll
  for (int i = 0; i < 2; ++i)
#pragma unroll
    for (int j = 0; j < 4; ++j)
#pragma unroll
      for (int rr = 0; rr < 4; ++rr) {
        int rloc = wrow + i * 16 + quad * 4 + rr;
        float v = acc[i][j][rr] / den_s[rloc];
        outI[(tok0 + rloc) * 1024 + h * 64 + j * 16 + lr] = f2b(v);
      }
}

extern "C" void kernel_launch(void* const* d_in, const int* in_sizes, int n_in,
                              void* d_out, int out_size, void* d_ws, size_t ws_size,
                              hipStream_t stream) {
  const float* x    = (const float*)d_in[0];
  const float* Wq   = (const float*)d_in[1];
  const float* Wk   = (const float*)d_in[2];
  const float* Wv   = (const float*)d_in[3];
  const float* proj = (const float*)d_in[4];
  const float* Wo   = (const float*)d_in[5];
  const float* bo   = (const float*)d_in[6];
  float* out = (float*)d_out;

  char* ws = (char*)d_ws;
  const size_t SZ = 1ull << 26;
  u16* xb     = (u16*)(ws + 0);
  u16* qb     = (u16*)(ws + SZ);
  u16* kb     = (u16*)(ws + 2 * SZ);   // kT[b,h,f,n]
  u16* vb     = (u16*)(ws + 3 * SZ);   // vT[b,h,d,n]
  u16* WqkvT  = (u16*)(ws + 4 * SZ);
  u16* woT    = (u16*)(ws + 4 * SZ + 0x600000);
  float* kvT    = (float*)(ws + 4 * SZ + 0x800000);             // 1 MB
  float* ksum   = (float*)(ws + 4 * SZ + 0x800000 + 0x100000);  // 16 KB (contiguous)

  prep<<<17668, 256, 0, stream>>>(x, Wq, Wk, Wv, Wo, proj, xb, WqkvT, woT, kvT);
  gemm256<12, true><<<1536, 512, 0, stream>>>(xb, WqkvT, qb, kb, vb, nullptr, nullptr);
  kv_mfma<<<dim3(64, 8), 256, 0, stream>>>(kb, vb, kvT, ksum);
  num_den<<<dim3(256, 16), 256, 0, stream>>>(qb, kvT, ksum, xb);
  gemm256<4, false><<<512, 512, 0, stream>>>(xb, woT, nullptr, nullptr, nullptr, out, bo);
}